// Round 1
// baseline (201.292 us; speedup 1.0000x reference)
//
#include <hip/hip_runtime.h>

#define NG 48
#define KMAX 14

__global__ void zero_kernel(float* __restrict__ out, int n) {
    int i = blockIdx.x * blockDim.x + threadIdx.x;
    if (i < n) out[i] = 0.0f;
}

// One block per (atom, type). blockIdx.x = atom, blockIdx.y = type.
// 256 threads: threads 0..195 own an (kx,ky) pair of the 14x14 xy-bbox and
// loop over kz, atomically adding valid in-sphere contributions.
__global__ __launch_bounds__(256) void splat_kernel(
    const float* __restrict__ vC,
    const float* __restrict__ vN,
    const float* __restrict__ vO,
    float* __restrict__ out)
{
    const int type = blockIdx.y;
    const float r = (type == 0) ? 1.7f : ((type == 1) ? 1.55f : 1.52f);
    const float* __restrict__ vecs = (type == 0) ? vC : ((type == 1) ? vN : vO);
    float* __restrict__ o = out + type * (NG * NG * NG);
    const int atom = blockIdx.x;

    __shared__ float sv[3];
    __shared__ int   smin[3];
    __shared__ int   smax[3];
    __shared__ float d2tab[3][KMAX];
    __shared__ int   vtab[3][KMAX];

    const int tid = threadIdx.x;

    if (tid < 3) {
        // vec = vecs + 48*0.5 - 0.5
        float v = vecs[atom * 3 + tid] + 24.0f - 0.5f;
        sv[tid] = v;
        float b = 1.5f * r;
        // (vec - b)/0.5 ; argument always > 0 so trunc == floor
        int mn = (int)((v - b) * 2.0f);
        mn = min(max(mn, 0), NG);
        int mx = (int)(2.0f + (v + b) * 2.0f);
        mx = min(max(mx, 0), NG);
        smin[tid] = mn;
        smax[tid] = mx;
    }
    __syncthreads();

    if (tid < 3 * KMAX) {
        int ax = tid / KMAX;
        int k  = tid - ax * KMAX;
        int idx = smin[ax] + k;
        float da = sv[ax] - 0.5f * (float)idx;
        d2tab[ax][k] = da * da;
        vtab[ax][k] = (idx < smax[ax]) ? 1 : 0;
    }
    __syncthreads();

    if (tid >= KMAX * KMAX) return;

    const int kx = tid / KMAX;
    const int ky = tid - kx * KMAX;
    if (!vtab[0][kx] || !vtab[1][ky]) return;

    const float rr     = r * r;
    const float r15    = 1.5f * r;
    const float r15sq  = r15 * r15;
    const float E2     = 7.389056205749512f;        // float(exp(2.0))
    const float c2a    = 4.0f / (E2 * rr);
    const float c2b    = 12.0f / (E2 * r);
    const float c2c    = 9.0f / E2;
    const float n2orr  = -2.0f / rr;

    const float sxy = d2tab[0][kx] + d2tab[1][ky];
    if (sxy >= r15sq) return;   // whole z-row outside the 1.5r sphere

    const int ix = smin[0] + kx;   // valid => ix < smax[0] <= 48
    const int iy = smin[1] + ky;
    const int z0 = smin[2];
    float* __restrict__ row = o + (ix * NG + iy) * NG + z0;

    for (int kz = 0; kz < KMAX; ++kz) {
        if (!vtab[2][kz]) break;           // validity is monotone in kz
        float d2 = sxy + d2tab[2][kz];
        if (d2 >= r15sq) continue;         // val would be 0
        float d = sqrtf(d2);
        float val;
        if (d < r) {
            val = expf(n2orr * d2);
        } else {
            val = c2a * d2 - c2b * d + c2c;   // continuous: f2(1.5r)=0, f2(r)=f1(r)
        }
        atomicAdd(&row[kz], val);
    }
}

extern "C" void kernel_launch(void* const* d_in, const int* in_sizes, int n_in,
                              void* d_out, int out_size, void* d_ws, size_t ws_size,
                              hipStream_t stream) {
    const float* vC = (const float*)d_in[0];
    const float* vN = (const float*)d_in[1];
    const float* vO = (const float*)d_in[2];
    float* out = (float*)d_out;

    // Zero the output grid (harness poisons it; we accumulate via atomics).
    int n = out_size;
    zero_kernel<<<(n + 255) / 256, 256, 0, stream>>>(out, n);

    const int natoms = in_sizes[0] / 3;   // 16384
    dim3 grid(natoms, 3, 1);
    splat_kernel<<<grid, 256, 0, stream>>>(vC, vN, vO, out);
}

// Round 2
// 169.508 us; speedup vs baseline: 1.1875x; 1.1875x over previous
//
#include <hip/hip_runtime.h>

#define NG 48
#define TS 8                 // tile edge in cells
#define NT 6                 // tiles per axis (6*8 = 48)
#define NTILES (NT * NT * NT)

// One block per (tile, type). 256 threads; each thread owns 2 cells of the
// 8x8x8 tile (x and x+4). Scan all atoms in 256-chunks, compact the ones whose
// 1.5r-bbox overlaps the tile into LDS (deterministic wave-ordered prefix),
// then gather-evaluate. No global atomics; every output cell stored once.
//
// Exactness note: the reference's min_pt/max_pt truncation window is a strict
// superset of the d < 1.5r support sphere (trunc(2(vec-b)) <= 2(vec-b) and
// trunc(2+2(vec+b)) > 2(vec+b); the [0,48] clips only exclude indices outside
// [0,47]). So gather predicate == d < 1.5r exactly.
__global__ __launch_bounds__(256) void splat_gather(
    const float* __restrict__ vC,
    const float* __restrict__ vN,
    const float* __restrict__ vO,
    float* __restrict__ out,
    int natoms)
{
    const int type = blockIdx.y;
    const float r = (type == 0) ? 1.7f : ((type == 1) ? 1.55f : 1.52f);
    const float* __restrict__ vecs = (type == 0) ? vC : ((type == 1) ? vN : vO);

    // Coprime-stride permutation spreads the (clustered) active tiles across CUs.
    const int t  = (int)((blockIdx.x * 151u) % NTILES);
    const int tx = t / (NT * NT);
    const int ty = (t / NT) % NT;
    const int tz = t % NT;

    const int tid  = threadIdx.x;
    const int lx   = tid >> 6;        // 0..3  (also the wave id)
    const int ly   = (tid >> 3) & 7;
    const int lz   = tid & 7;
    const int lane = tid & 63;

    const float b      = 1.5f * r;
    const float r15sq  = b * b;
    const float rr     = r * r;
    const float E2     = 7.3890562f;           // float(exp(2))
    const float c2a    = 4.0f / (E2 * rr);
    const float c2b    = 12.0f / (E2 * r);
    const float c2c    = 9.0f / E2;
    const float n2orr  = -2.0f / rr;

    const float px0 = 0.5f * (float)(tx * TS + lx);
    const float px1 = px0 + 2.0f;              // x + 4 cells = +2.0 A
    const float py  = 0.5f * (float)(ty * TS + ly);
    const float pz  = 0.5f * (float)(tz * TS + lz);

    // tile acceptance box: atom can contribute iff within b of some cell center
    const float lox = 0.5f * (float)(tx * TS) - b;
    const float hix = 0.5f * (float)(tx * TS + TS - 1) + b;
    const float loy = 0.5f * (float)(ty * TS) - b;
    const float hiy = 0.5f * (float)(ty * TS + TS - 1) + b;
    const float loz = 0.5f * (float)(tz * TS) - b;
    const float hiz = 0.5f * (float)(tz * TS + TS - 1) + b;

    __shared__ float sax[256], say[256], saz[256];
    __shared__ int wcnt[4];

    float acc0 = 0.0f, acc1 = 0.0f;

    for (int base0 = 0; base0 < natoms; base0 += 256) {
        const int i = base0 + tid;
        bool pass = false;
        float vx = 0.0f, vy = 0.0f, vz = 0.0f;
        if (i < natoms) {
            vx = vecs[i * 3 + 0] + 23.5f;   // vec = vecs + 48*0.5 - 0.5
            vy = vecs[i * 3 + 1] + 23.5f;
            vz = vecs[i * 3 + 2] + 23.5f;
            pass = (vx > lox) & (vx < hix) & (vy > loy) & (vy < hiy)
                 & (vz > loz) & (vz < hiz);
        }
        const unsigned long long m = __ballot(pass);
        if (lane == 0) wcnt[lx] = (int)__popcll(m);
        __syncthreads();
        int off = 0;
        #pragma unroll
        for (int w = 0; w < 4; ++w) if (w < lx) off += wcnt[w];
        const int tot = wcnt[0] + wcnt[1] + wcnt[2] + wcnt[3];
        if (pass) {
            const int pos = off + (int)__popcll(m & ((1ull << lane) - 1ull));
            sax[pos] = vx; say[pos] = vy; saz[pos] = vz;
        }
        __syncthreads();

        for (int j = 0; j < tot; ++j) {
            const float ax = sax[j], ay = say[j], az = saz[j];  // LDS broadcast
            const float dy  = ay - py;
            const float dz  = az - pz;
            const float syz = fmaf(dy, dy, dz * dz);
            const float dx0 = ax - px0;
            const float d2a = fmaf(dx0, dx0, syz);
            const float dx1 = ax - px1;
            const float d2b = fmaf(dx1, dx1, syz);
            if (d2a < r15sq) {
                const float d = sqrtf(d2a);
                acc0 += (d < r) ? __expf(n2orr * d2a)
                                : fmaf(c2a, d2a, fmaf(-c2b, d, c2c));
            }
            if (d2b < r15sq) {
                const float d = sqrtf(d2b);
                acc1 += (d < r) ? __expf(n2orr * d2b)
                                : fmaf(c2a, d2b, fmaf(-c2b, d, c2c));
            }
        }
        __syncthreads();
    }

    const int X0 = tx * TS + lx;
    const int Y  = ty * TS + ly;
    const int Z  = tz * TS + lz;
    float* __restrict__ o = out + (size_t)type * NG * NG * NG;
    o[((X0       * NG) + Y) * NG + Z] = acc0;
    o[(((X0 + 4) * NG) + Y) * NG + Z] = acc1;
}

extern "C" void kernel_launch(void* const* d_in, const int* in_sizes, int n_in,
                              void* d_out, int out_size, void* d_ws, size_t ws_size,
                              hipStream_t stream) {
    const float* vC = (const float*)d_in[0];
    const float* vN = (const float*)d_in[1];
    const float* vO = (const float*)d_in[2];
    float* out = (float*)d_out;

    const int natoms = in_sizes[0] / 3;   // 16384
    dim3 grid(NTILES, 3, 1);
    splat_gather<<<grid, 256, 0, stream>>>(vC, vN, vO, out, natoms);
}